// Round 10
// baseline (122.312 us; speedup 1.0000x reference)
//
#include <hip/hip_runtime.h>
#include <cmath>

#define B_ 2
#define X_ 128
#define Y_ 128
#define Z_ 128
#define C_ 8
#define ZC 1024         // Z_*C_
#define XS 131072       // Y_*ZC, stride of x in elements
#define BS 16777216     // X_*XS, stride of batch in elements
#define PF4 32768       // float4s per (b,x) plane
#define KTAPS 13
#define TAIL 6

struct Taps { float k[KTAPS]; };

__device__ __forceinline__ float4 ld4(const float* p) {
    return *reinterpret_cast<const float4*>(p);
}
__device__ __forceinline__ void st4(float* p, const float4& v) {
    *reinterpret_cast<float4*>(p) = v;
}
__device__ __forceinline__ float4 f4zero() { return make_float4(0.f, 0.f, 0.f, 0.f); }
__device__ __forceinline__ void fma4(float4& a, float s, const float4& b) {
    a.x = fmaf(s, b.x, a.x); a.y = fmaf(s, b.y, a.y);
    a.z = fmaf(s, b.z, a.z); a.w = fmaf(s, b.w, a.w);
}

// ---------------- Pass 1: PURE-STREAM conv along Y ---------------------------
// R8/R9 lesson: the cold pass was latency-bound because per-iteration barriers
// (vmcnt(0)-draining __syncthreads, or my over-strong sched_barrier(0)) killed
// cross-iteration load pipelining. This pass has NO LDS, NO barriers, NO
// fences: register 13-row window + P-deep rotating prefetch, contiguous
// marching loads AND stores (+4KB/iter). Structurally a copy kernel with FMAs;
// the compiler is free to software-pipeline. Z-conv moved to pass 2.
template <int SEG, int P>
__global__ __launch_bounds__(256, 3) void yconv_stream(const float* __restrict__ src,
                                                       float* __restrict__ dst,
                                                       Taps tp) {
    const int t = threadIdx.x;                  // 0..255, covers full zc row
    const int s = blockIdx.x & (SEG - 1);       // s inner: consecutive blocks
    const int x = (blockIdx.x >> 2) & (X_ - 1); //  cover a plane densely (SEG=4)
    const int b = blockIdx.x >> 9;

    const int pbase = b * BS + x * XS;
    const int zc    = t << 2;
    const int ylen  = Y_ / SEG;
    const int y0    = s * ylen;

    auto ldrow = [&](int yy) -> float4 {
        return (yy >= 0 && yy < Y_) ? ld4(src + pbase + yy * ZC + zc) : f4zero();
    };

    float4 w[KTAPS - 1];                        // rows y-6..y+5
#pragma unroll
    for (int i = 0; i < KTAPS - 1; ++i) w[i] = ldrow(y0 - TAIL + i);
    float4 pf[P];                               // rows y+6..y+6+P-1 in flight
#pragma unroll
    for (int i = 0; i < P; ++i) pf[i] = ldrow(y0 + TAIL + i);

    for (int yy = 0; yy < ylen; yy += P) {
#pragma unroll
        for (int k = 0; k < P; ++k) {           // pf[k] static index (rule #20)
            const int y = y0 + yy + k;
            const float4 cur = pf[k];           // row y+6
            pf[k] = ldrow(y + TAIL + P);        // refill; consumed P iters later

            float4 acc = f4zero();
#pragma unroll
            for (int i = 0; i < KTAPS - 1; ++i) fma4(acc, tp.k[i], w[i]);
            fma4(acc, tp.k[KTAPS - 1], cur);
            st4(dst + pbase + y * ZC + zc, acc);

#pragma unroll
            for (int i = 0; i < KTAPS - 2; ++i) w[i] = w[i + 1];
            w[KTAPS - 2] = cur;
        }
    }
}

// ------------- Pass 2: X-conv gather (L3-warm) + Z-conv via LDS row ----------
// Block = 256 threads = one zc row at (b, y), x-window of W=16. The 28-plane
// pinned burst (proven 33us on warm tmp) computes the X-conv; each result row
// is staged in LDS (double-buffered) and the Z-conv reads 13 z-neighbors.
// Barrier is lgkmcnt-only (no vmcnt drain -> no waiting on the 16 posted
// plane-writes or the remaining burst loads).
template <int W, bool DOZ>
__global__ __launch_bounds__(256, 1) void xzconv(const float* __restrict__ src,
                                                 float* __restrict__ dst,
                                                 Taps tp) {
    __shared__ float row[2][ZC];

    const int t   = threadIdx.x;
    const int gid = blockIdx.x;
    const int y   = (Y_ - 1) - (gid & (Y_ - 1));   // reversed: hit last-written tmp
    const int xw  = (gid >> 7) & (X_ / W - 1);
    const int b   = gid >> 10;

    const int x0   = xw * W;
    const int base = b * BS + y * ZC + (t << 2);   // this thread's f4 at plane x=0
    const int z    = t >> 1;
    const int cw   = (t & 1) << 2;

    float4 v[W + 2 * TAIL];
#pragma unroll
    for (int i = 0; i < W + 2 * TAIL; ++i) {
        const int xx = x0 - TAIL + i;
        v[i] = (xx >= 0 && xx < X_) ? ld4(src + base + xx * XS) : f4zero();
    }
#pragma unroll
    for (int i = 0; i < W + 2 * TAIL; ++i) {
        asm volatile("" : "+v"(v[i].x), "+v"(v[i].y), "+v"(v[i].z), "+v"(v[i].w));
    }
    __builtin_amdgcn_sched_barrier(0);

    int pp = 0;
#pragma unroll
    for (int j = 0; j < W; ++j) {
        float4 acc = f4zero();
#pragma unroll
        for (int i = 0; i < KTAPS; ++i) fma4(acc, tp.k[i], v[j + i]);

        if (DOZ) {
            st4(&row[pp][t << 2], acc);
            // LDS-only visibility: wait ds ops, raw barrier, pin order.
            asm volatile("s_waitcnt lgkmcnt(0)" ::: "memory");
            __builtin_amdgcn_s_barrier();
            __builtin_amdgcn_sched_barrier(0);

            float4 zacc = f4zero();
#pragma unroll
            for (int i = 0; i < KTAPS; ++i) {
                const int zz = z - TAIL + i;
                if (zz >= 0 && zz < Z_) {
                    fma4(zacc, tp.k[i], ld4(&row[pp][(zz << 3) + cw]));
                }
            }
            st4(dst + base + (x0 + j) * XS, zacc);
            pp ^= 1;
            // safe: reads of row[pp] data-complete (lgkmcnt0) before each
            // wave's next barrier; rewrite of same buffer is 2 barriers away.
        } else {
            st4(dst + base + (x0 + j) * XS, acc);
        }
    }
}

// -------- Fallback-only: fused Y+Z, single plane per block, in-place-safe ----
template <int SEGY, int P>
__global__ __launch_bounds__(256) void yzconv_kernel(const float* __restrict__ src,
                                                     float* __restrict__ dst,
                                                     Taps tp) {
    __shared__ float row[2][ZC];

    const int t    = threadIdx.x;
    const int s    = blockIdx.x % SEGY;
    const int rest = blockIdx.x / SEGY;
    const int x    = rest & (X_ - 1);
    const int b    = rest >> 7;

    const int pbase = b * BS + x * XS;
    const int zc    = t << 2;
    const int z     = t >> 1;
    const int cw    = (t & 1) << 2;

    const int ylen = Y_ / SEGY;
    const int y0   = s * ylen;

    auto ldrow = [&](int yy) -> float4 {
        return (yy >= 0 && yy < Y_) ? ld4(src + pbase + yy * ZC + zc) : f4zero();
    };

    float4 w[KTAPS];
#pragma unroll
    for (int i = 0; i < KTAPS - 1; ++i) w[i] = ldrow(y0 - TAIL + i);
    float4 pf[P];
#pragma unroll
    for (int i = 0; i < P; ++i) pf[i] = ldrow(y0 + TAIL + i);

    int p = 0;
    for (int yy = 0; yy < ylen; yy += P) {
#pragma unroll
        for (int k = 0; k < P; ++k) {
            const int y = y0 + yy + k;
            w[KTAPS - 1] = pf[k];
            pf[k] = ldrow(y + TAIL + P);

            float4 acc = f4zero();
#pragma unroll
            for (int i = 0; i < KTAPS; ++i) fma4(acc, tp.k[i], w[i]);
            st4(&row[p][zc], acc);
            asm volatile("s_waitcnt lgkmcnt(0)" ::: "memory");
            __builtin_amdgcn_s_barrier();
            __builtin_amdgcn_sched_barrier(0);

            float4 zacc = f4zero();
#pragma unroll
            for (int i = 0; i < KTAPS; ++i) {
                const int zz = z - TAIL + i;
                if (zz >= 0 && zz < Z_) {
                    fma4(zacc, tp.k[i], ld4(&row[p][(zz << 3) + cw]));
                }
            }
            st4(dst + pbase + y * ZC + zc, zacc);

#pragma unroll
            for (int i = 0; i < KTAPS - 1; ++i) w[i] = w[i + 1];
            p ^= 1;
        }
    }
}

extern "C" void kernel_launch(void* const* d_in, const int* in_sizes, int n_in,
                              void* d_out, int out_size, void* d_ws, size_t ws_size,
                              hipStream_t stream) {
    const float* in = (const float*)d_in[0];
    float* out = (float*)d_out;

    // Gaussian taps: tail = int(2.0*3.0 + 0.5) = 6, K = 13, sigma = 2
    Taps tp;
    {
        float kv[KTAPS];
        float sum = 0.f;
        for (int i = 0; i < KTAPS; ++i) {
            const float xx = (float)(i - TAIL);
            kv[i] = expf(-0.5f * xx * xx / 4.0f);
            sum += kv[i];
        }
        for (int i = 0; i < KTAPS; ++i) tp.k[i] = kv[i] / sum;
    }

    const size_t need_bytes = (size_t)B_ * BS * sizeof(float);  // 134 MB
    const bool use_ws = (ws_size >= need_bytes) && (d_ws != nullptr);
    float* tmp = use_ws ? (float*)d_ws : out;

    if (use_ws) {
        // Pass 1: pure-stream Y conv, in (cold) -> tmp. SEG=4: 1024 blocks,
        // 16 waves/CU, no barriers -> compiler-pipelined deep prefetch.
        yconv_stream<4, 4><<<B_ * X_ * 4, 256, 0, stream>>>(in, tmp, tp);
        // Pass 2: X gather (tmp L3-warm) + Z via LDS -> out. 2048 blocks.
        xzconv<16, true><<<B_ * (X_ / 16) * Y_, 256, 0, stream>>>(tmp, out, tp);
    } else {
        // Fallback (never expected): X-only gather in->out, then in-place
        // fused Y+Z per plane (block-local, writes trail reads).
        xzconv<16, false><<<B_ * (X_ / 16) * Y_, 256, 0, stream>>>(in, out, tp);
        yzconv_kernel<1, 4><<<B_ * X_, 256, 0, stream>>>(out, out, tp);
    }
}